// Round 7
// baseline (283.939 us; speedup 1.0000x reference)
//
#include <hip/hip_runtime.h>
#include <hip/hip_bf16.h>
#include <stdint.h>

#define NE 8
#define HID 1024
#define FFN 4096
#define TOK 8192
#define TPE (TOK / NE)   // 1024 tokens per expert

typedef __attribute__((ext_vector_type(8))) short    bf16x8;
typedef __attribute__((ext_vector_type(4))) float    f32x4;
typedef __attribute__((ext_vector_type(4))) unsigned short ushort4v;
typedef __attribute__((ext_vector_type(8))) unsigned short ushort8v;

// ---------- helpers ----------

__device__ __forceinline__ unsigned short f2bf(float f) {
    union { float f; unsigned u; } c; c.f = f;
    unsigned r = c.u + 0x7fffu + ((c.u >> 16) & 1u);   // RNE, inputs finite
    return (unsigned short)(r >> 16);
}

__device__ __forceinline__ float gelu_tanh(float x) {
    const float c0 = 0.7978845608028654f;  // sqrt(2/pi)
    const float c1 = 0.044715f;
    float u = c0 * (x + c1 * x * x * x);
    float t = 1.0f - 2.0f / (1.0f + __expf(2.0f * u));
    return 0.5f * x * (1.0f + t);
}

typedef const __attribute__((address_space(1))) void gbl_void_t;
typedef __attribute__((address_space(3))) void lds_void_t;

__device__ __forceinline__ void gload_lds16(const void* g, void* l) {
    __builtin_amdgcn_global_load_lds((gbl_void_t*)g, (lds_void_t*)l, 16, 0, 0);
}

// ---------- conversion: f32 -> bf16, 8 elems/thread ----------

__global__ void cvt_f32_bf16(const float* __restrict__ in,
                             unsigned short* __restrict__ out) {
    size_t i = ((size_t)blockIdx.x * blockDim.x + threadIdx.x) * 8;
    f32x4 a = *(const f32x4*)(in + i);
    f32x4 b = *(const f32x4*)(in + i + 4);
    ushort8v o;
#pragma unroll
    for (int j = 0; j < 4; j++) { o[j] = f2bf(a[j]); o[4 + j] = f2bf(b[j]); }
    *(ushort8v*)(out + i) = o;
}

// ---------- transpose-convert: w2 [E][F][H] f32 -> w2t [E][H][F] bf16 ----------

__global__ void transpose_cvt(const float* __restrict__ in,
                              unsigned short* __restrict__ out) {
    __shared__ unsigned short tile[64][65];
    const int e  = blockIdx.z;
    const int f0 = blockIdx.x * 64;
    const int h0 = blockIdx.y * 64;
    const float*     src = in  + (size_t)e * FFN * HID;
    unsigned short*  dst = out + (size_t)e * HID * FFN;
    const int t  = threadIdx.x;
    const int tr = t >> 4;        // 0..15
    const int tc = (t & 15) * 4;  // 0..60
#pragma unroll
    for (int i = 0; i < 4; i++) {
        int f = i * 16 + tr;
        f32x4 v = *(const f32x4*)(src + (size_t)(f0 + f) * HID + h0 + tc);
#pragma unroll
        for (int j = 0; j < 4; j++) tile[f][tc + j] = f2bf(v[j]);
    }
    __syncthreads();
#pragma unroll
    for (int i = 0; i < 4; i++) {
        int h = i * 16 + tr;
        ushort4v o;
#pragma unroll
        for (int j = 0; j < 4; j++) o[j] = tile[tc + j][h];
        *(ushort4v*)(dst + (size_t)(h0 + h) * FFN + f0 + tc) = o;
    }
}

// ---------- GEMM-BT: TLP-first diet kernel -------------------------------
// C[M][N] = A[M][K]*B[N][K]^T per expert. 128x128 tile, BK=64, 4 waves (2x2),
// 256 threads, SINGLE-buffered 32KB LDS, 2 barriers/K-step (m97 discipline;
// compiler emits fine-grained lgkm waits). T2 XOR swizzle (linear LDS dest,
// pre-swizzled source, swizzled read — proven 0-conflict). T1 XCD swizzle:
// one expert per XCD for GEMM1. Optional split-K (NS) for grid depth.
// VGPR diet: acc 4x4 (64 AGPR) + slice-wise frags; launch_bounds(256,4)
// targets 4 blocks/CU co-resident -> TLP hides barrier/vmcnt stalls.

template <int GX, int GY, int NS, bool GELU>
__global__ __launch_bounds__(256, 4)
void gemm_dw(const unsigned short* __restrict__ A,
             const unsigned short* __restrict__ B,
             void* __restrict__ Cout, int M, int N, int K) {
    constexpr int NWG = NE * GX * GY * NS;

    __shared__ __align__(16) char lds[32768];   // A: 16KB, B: 16KB

    // ---- XCD-aware bijective swizzle (T1) ----
    const int lin = blockIdx.x;
    const int wid = (lin & 7) * (NWG >> 3) + (lin >> 3);
    const int e   = wid / (GX * GY * NS);
    int r         = wid % (GX * GY * NS);
    const int ny  = r / (GX * NS);
    r             = r % (GX * NS);
    const int nx  = r / NS;
    const int ks  = r % NS;

    const int m0 = nx * 128;
    const int n0 = ny * 128;
    const int KL = K / NS;            // K-range per block
    const int k0 = ks * KL;

    const size_t K2 = (size_t)K * 2;
    const char* Ae = (const char*)(A + (size_t)e * M * K);
    const char* Be = (const char*)(B + (size_t)e * N * K);

    const int tid  = threadIdx.x;
    const int lane = tid & 63;
    const int w    = tid >> 6;
    const int wr   = w >> 1, wc = w & 1;
    const int fr   = lane & 15, fq = lane >> 4;

    // ---- staging: 4 gloads per matrix per thread; shared swizzle across i ----
    // chunk c = tid + 256*i: row = (tid>>3) + 32*i, kb=(tid&7)*16; (row&7)==(tid>>3)&7
    const int r0  = tid >> 3;
    const int kb  = (tid & 7) * 16;
    const int kbs = kb ^ ((r0 & 7) << 4);
    const char* abase = Ae + (size_t)(m0 + r0) * K2 + (size_t)k0 * 2 + kbs;
    const char* bbase = Be + (size_t)(n0 + r0) * K2 + (size_t)k0 * 2 + kbs;
    char* dA = lds + tid * 16;          // linear dest: chunk c at lds + c*16
    char* dB = lds + 16384 + tid * 16;

    // ---- swizzled read cols (shared across m/n since rows off by mult of 8) ----
    const int swz  = (fr & 7) << 4;
    const int col0 = (fq * 16) ^ swz;          // k-slice 0
    const int col1 = (64 + fq * 16) ^ swz;     // k-slice 1
    const char* pA = lds + (wr * 64 + fr) * 128;
    const char* pB = lds + 16384 + (wc * 64 + fr) * 128;

    f32x4 acc[4][4];
#pragma unroll
    for (int i = 0; i < 4; i++)
#pragma unroll
        for (int j = 0; j < 4; j++) acc[i][j] = f32x4{0.f, 0.f, 0.f, 0.f};

    const int NT = KL / 64;
    for (int it = 0; it < NT; ++it) {
        const size_t kt = (size_t)it * 128;    // byte advance along K
#pragma unroll
        for (int i = 0; i < 4; i++)
            gload_lds16(abase + kt + (size_t)(32 * i) * K2, dA + i * 4096);
#pragma unroll
        for (int i = 0; i < 4; i++)
            gload_lds16(bbase + kt + (size_t)(32 * i) * K2, dB + i * 4096);
        __syncthreads();                       // drains vmcnt before reads

        bf16x8 af[4], bf[4];
#pragma unroll
        for (int s = 0; s < 2; s++) {
            const int cs = s ? col1 : col0;
#pragma unroll
            for (int m = 0; m < 4; m++) af[m] = *(const bf16x8*)(pA + m * 2048 + cs);
#pragma unroll
            for (int n = 0; n < 4; n++) bf[n] = *(const bf16x8*)(pB + n * 2048 + cs);
            __builtin_amdgcn_s_setprio(1);
#pragma unroll
            for (int m = 0; m < 4; m++)
#pragma unroll
                for (int n = 0; n < 4; n++)
                    acc[m][n] = __builtin_amdgcn_mfma_f32_16x16x32_bf16(
                        af[m], bf[n], acc[m][n], 0, 0, 0);
            __builtin_amdgcn_s_setprio(0);
        }
        __syncthreads();                       // protect LDS before next stage
    }

    // epilogue: C/D layout col = lane&15, row = (lane>>4)*4 + rr
    const int orow = m0 + wr * 64 + fq * 4;
    const int ocol = n0 + wc * 64 + fr;
    if constexpr (GELU) {
        unsigned short* C = (unsigned short*)Cout + (size_t)e * M * N;
#pragma unroll
        for (int m = 0; m < 4; m++)
#pragma unroll
            for (int n = 0; n < 4; n++) {
                int row = orow + m * 16, col = ocol + n * 16;
#pragma unroll
                for (int rr = 0; rr < 4; rr++)
                    C[(size_t)(row + rr) * N + col] = f2bf(gelu_tanh(acc[m][n][rr]));
            }
    } else {
        // split-K partial: [ks][e][M][N] f32
        float* C = (float*)Cout + ((size_t)(ks * NE + e) * M) * N;
#pragma unroll
        for (int m = 0; m < 4; m++)
#pragma unroll
            for (int n = 0; n < 4; n++) {
                int row = orow + m * 16, col = ocol + n * 16;
#pragma unroll
                for (int rr = 0; rr < 4; rr++)
                    C[(size_t)(row + rr) * N + col] = acc[m][n][rr];
            }
    }
}

// ---------- combine split-K partials: out = p0 + p1 ----------

__global__ void combine_f32(const float* __restrict__ p0,
                            const float* __restrict__ p1,
                            float* __restrict__ out) {
    size_t i = ((size_t)blockIdx.x * blockDim.x + threadIdx.x) * 4;
    f32x4 a = *(const f32x4*)(p0 + i);
    f32x4 b = *(const f32x4*)(p1 + i);
    *(f32x4*)(out + i) = a + b;
}

// ---------- fallback: fused fp32, zero workspace (correctness insurance) ----------

__global__ void fused_fallback(const float* __restrict__ x,
                               const float* __restrict__ w1,
                               const float* __restrict__ w2,
                               float* __restrict__ out) {
    __shared__ float xs[HID];
    __shared__ float hs[FFN];
    const int tok = blockIdx.x;
    const int e   = tok / TPE;
    const float* w1e = w1 + (size_t)e * FFN * HID;
    const float* w2e = w2 + (size_t)e * FFN * HID;
    const int t = threadIdx.x;
    for (int i = t; i < HID; i += 256) xs[i] = x[(size_t)tok * HID + i];
    __syncthreads();
    for (int f = t; f < FFN; f += 256) {
        const float* wr_ = w1e + (size_t)f * HID;
        float s = 0.f;
        for (int k = 0; k < HID; k++) s += xs[k] * wr_[k];
        hs[f] = gelu_tanh(s);
    }
    __syncthreads();
    for (int h = t; h < HID; h += 256) {
        float s = 0.f;
        for (int f = 0; f < FFN; f++) s += hs[f] * w2e[(size_t)f * HID + h];
        out[(size_t)tok * HID + h] = s;
    }
}

// ---------- launch ----------

extern "C" void kernel_launch(void* const* d_in, const int* in_sizes, int n_in,
                              void* d_out, int out_size, void* d_ws, size_t ws_size,
                              hipStream_t stream) {
    const float* x  = (const float*)d_in[0];
    const float* w1 = (const float*)d_in[1];
    const float* w2 = (const float*)d_in[2];
    float* out = (float*)d_out;

    const size_t XB  = (size_t)TOK * HID * 2;        // 16 MB  bf16 x
    const size_t W1B = (size_t)NE * FFN * HID * 2;   // 64 MB  bf16 w1
    const size_t W2B = W1B;                          // 64 MB  bf16 w2t
    const size_t HB  = (size_t)TOK * FFN * 2;        // 64 MB  bf16 h
    const size_t need = XB + W1B + W2B + HB;         // 208 MB

    if (ws_size >= need) {
        char* ws = (char*)d_ws;
        unsigned short* xb  = (unsigned short*)ws;
        unsigned short* w1b = (unsigned short*)(ws + XB);
        unsigned short* w2t = (unsigned short*)(ws + XB + W1B);
        unsigned short* hb  = (unsigned short*)(ws + XB + W1B + W2B);
        // split-K partials (2 x 32MB f32) overlay xb+w1b (dead after GEMM1)
        float* part = (float*)ws;
        const size_t PSTRIDE = (size_t)TOK * HID;    // elems per partial

        cvt_f32_bf16<<<(TOK * HID) / (256 * 8), 256, 0, stream>>>(x, xb);
        cvt_f32_bf16<<<(NE * FFN * HID) / (256 * 8), 256, 0, stream>>>(w1, w1b);
        transpose_cvt<<<dim3(FFN / 64, HID / 64, NE), 256, 0, stream>>>(w2, w2t);

        // GEMM1: h = gelu(x @ w1^T)  M=1024,N=4096,K=1024/expert -> 2048 blocks
        gemm_dw<TPE / 128, FFN / 128, 1, true>
            <<<NE * (TPE / 128) * (FFN / 128), 256, 0, stream>>>(
                xb, w1b, hb, TPE, FFN, HID);
        // GEMM2: split-K x2 -> 1024 blocks, f32 partials
        gemm_dw<TPE / 128, HID / 128, 2, false>
            <<<NE * (TPE / 128) * (HID / 128) * 2, 256, 0, stream>>>(
                hb, w2t, part, TPE, HID, FFN);
        // out = p0 + p1
        combine_f32<<<(TOK * HID) / (256 * 4), 256, 0, stream>>>(
            part, part + PSTRIDE, out);
    } else {
        fused_fallback<<<TOK, 256, 0, stream>>>(x, w1, w2, out);
    }
}

// Round 8
// 268.158 us; speedup vs baseline: 1.0588x; 1.0588x over previous
//
#include <hip/hip_runtime.h>
#include <hip/hip_bf16.h>
#include <stdint.h>

#define NE 8
#define HID 1024
#define FFN 4096
#define TOK 8192
#define TPE (TOK / NE)   // 1024 tokens per expert

typedef __attribute__((ext_vector_type(8))) short    bf16x8;
typedef __attribute__((ext_vector_type(4))) float    f32x4;
typedef __attribute__((ext_vector_type(4))) unsigned short ushort4v;
typedef __attribute__((ext_vector_type(8))) unsigned short ushort8v;

// ---------- helpers ----------

__device__ __forceinline__ unsigned short f2bf(float f) {
    union { float f; unsigned u; } c; c.f = f;
    unsigned r = c.u + 0x7fffu + ((c.u >> 16) & 1u);   // RNE, inputs finite
    return (unsigned short)(r >> 16);
}

__device__ __forceinline__ float gelu_tanh(float x) {
    const float c0 = 0.7978845608028654f;  // sqrt(2/pi)
    const float c1 = 0.044715f;
    float u = c0 * (x + c1 * x * x * x);
    float t = 1.0f - 2.0f / (1.0f + __expf(2.0f * u));
    return 0.5f * x * (1.0f + t);
}

typedef const __attribute__((address_space(1))) void gbl_void_t;
typedef __attribute__((address_space(3))) void lds_void_t;

__device__ __forceinline__ void gload_lds16(const void* g, void* l) {
    __builtin_amdgcn_global_load_lds((gbl_void_t*)g, (lds_void_t*)l, 16, 0, 0);
}

// ---------- conversion: f32 -> bf16, 8 elems/thread ----------

__global__ void cvt_f32_bf16(const float* __restrict__ in,
                             unsigned short* __restrict__ out) {
    size_t i = ((size_t)blockIdx.x * blockDim.x + threadIdx.x) * 8;
    f32x4 a = *(const f32x4*)(in + i);
    f32x4 b = *(const f32x4*)(in + i + 4);
    ushort8v o;
#pragma unroll
    for (int j = 0; j < 4; j++) { o[j] = f2bf(a[j]); o[4 + j] = f2bf(b[j]); }
    *(ushort8v*)(out + i) = o;
}

// ---------- transpose-convert: w2 [E][F][H] f32 -> w2t [E][H][F] bf16 ----------

__global__ void transpose_cvt(const float* __restrict__ in,
                              unsigned short* __restrict__ out) {
    __shared__ unsigned short tile[64][65];
    const int e  = blockIdx.z;
    const int f0 = blockIdx.x * 64;
    const int h0 = blockIdx.y * 64;
    const float*     src = in  + (size_t)e * FFN * HID;
    unsigned short*  dst = out + (size_t)e * HID * FFN;
    const int t  = threadIdx.x;
    const int tr = t >> 4;        // 0..15
    const int tc = (t & 15) * 4;  // 0..60
#pragma unroll
    for (int i = 0; i < 4; i++) {
        int f = i * 16 + tr;
        f32x4 v = *(const f32x4*)(src + (size_t)(f0 + f) * HID + h0 + tc);
#pragma unroll
        for (int j = 0; j < 4; j++) tile[f][tc + j] = f2bf(v[j]);
    }
    __syncthreads();
#pragma unroll
    for (int i = 0; i < 4; i++) {
        int h = i * 16 + tr;
        ushort4v o;
#pragma unroll
        for (int j = 0; j < 4; j++) o[j] = tile[tc + j][h];
        *(ushort4v*)(dst + (size_t)(h0 + h) * FFN + f0 + tc) = o;
    }
}

// ---------- GEMM-BT: TLP-first diet kernel (no split-K) -------------------
// C[M][N] = A[M][K]*B[N][K]^T per expert. 128x128 tile, BK=64, 4 waves (2x2),
// 256 threads, SINGLE-buffered 32KB LDS, 2 barriers/K-step (m97 discipline).
// T2 XOR swizzle (linear LDS dest, pre-swizzled source, swizzled read —
// proven 0-conflict). T1 bijective XCD swizzle. VGPR diet (64 reported) ->
// multiple blocks/CU co-resident; TLP hides barrier/vmcnt stalls.

template <int GX, int GY, bool GELU>
__global__ __launch_bounds__(256, 4)
void gemm_dw(const unsigned short* __restrict__ A,
             const unsigned short* __restrict__ B,
             void* __restrict__ Cout, int M, int N, int K) {
    constexpr int NWG = NE * GX * GY;

    __shared__ __align__(16) char lds[32768];   // A: 16KB, B: 16KB

    // ---- XCD-aware bijective swizzle (T1) ----
    const int lin = blockIdx.x;
    const int wid = (lin & 7) * (NWG >> 3) + (lin >> 3);
    const int e   = wid / (GX * GY);
    int r         = wid % (GX * GY);
    const int ny  = r / GX;
    const int nx  = r % GX;

    const int m0 = nx * 128;
    const int n0 = ny * 128;

    const size_t K2 = (size_t)K * 2;
    const char* Ae = (const char*)(A + (size_t)e * M * K);
    const char* Be = (const char*)(B + (size_t)e * N * K);

    const int tid  = threadIdx.x;
    const int lane = tid & 63;
    const int w    = tid >> 6;
    const int wr   = w >> 1, wc = w & 1;
    const int fr   = lane & 15, fq = lane >> 4;

    // ---- staging: 4 gloads per matrix per thread; shared swizzle across i ----
    // chunk c = tid + 256*i: row = (tid>>3) + 32*i, kb=(tid&7)*16; (row&7)==(tid>>3)&7
    const int r0  = tid >> 3;
    const int kb  = (tid & 7) * 16;
    const int kbs = kb ^ ((r0 & 7) << 4);
    const char* abase = Ae + (size_t)(m0 + r0) * K2 + kbs;
    const char* bbase = Be + (size_t)(n0 + r0) * K2 + kbs;
    char* dA = lds + tid * 16;          // linear dest: chunk c at lds + c*16
    char* dB = lds + 16384 + tid * 16;

    // ---- swizzled read cols (shared across m/n since rows off by mult of 8) ----
    const int swz  = (fr & 7) << 4;
    const int col0 = (fq * 16) ^ swz;          // k-slice 0
    const int col1 = (64 + fq * 16) ^ swz;     // k-slice 1
    const char* pA = lds + (wr * 64 + fr) * 128;
    const char* pB = lds + 16384 + (wc * 64 + fr) * 128;

    f32x4 acc[4][4];
#pragma unroll
    for (int i = 0; i < 4; i++)
#pragma unroll
        for (int j = 0; j < 4; j++) acc[i][j] = f32x4{0.f, 0.f, 0.f, 0.f};

    const int NT = K / 64;
    for (int it = 0; it < NT; ++it) {
        const size_t kt = (size_t)it * 128;    // byte advance along K
#pragma unroll
        for (int i = 0; i < 4; i++)
            gload_lds16(abase + kt + (size_t)(32 * i) * K2, dA + i * 4096);
#pragma unroll
        for (int i = 0; i < 4; i++)
            gload_lds16(bbase + kt + (size_t)(32 * i) * K2, dB + i * 4096);
        __syncthreads();                       // drains vmcnt before reads

        bf16x8 af[4], bf[4];
#pragma unroll
        for (int s = 0; s < 2; s++) {
            const int cs = s ? col1 : col0;
#pragma unroll
            for (int m = 0; m < 4; m++) af[m] = *(const bf16x8*)(pA + m * 2048 + cs);
#pragma unroll
            for (int n = 0; n < 4; n++) bf[n] = *(const bf16x8*)(pB + n * 2048 + cs);
            __builtin_amdgcn_s_setprio(1);
#pragma unroll
            for (int m = 0; m < 4; m++)
#pragma unroll
                for (int n = 0; n < 4; n++)
                    acc[m][n] = __builtin_amdgcn_mfma_f32_16x16x32_bf16(
                        af[m], bf[n], acc[m][n], 0, 0, 0);
            __builtin_amdgcn_s_setprio(0);
        }
        __syncthreads();                       // protect LDS before next stage
    }

    // epilogue: C/D layout col = lane&15, row = (lane>>4)*4 + rr
    const int orow = m0 + wr * 64 + fq * 4;
    const int ocol = n0 + wc * 64 + fr;
    if constexpr (GELU) {
        unsigned short* C = (unsigned short*)Cout + (size_t)e * M * N;
#pragma unroll
        for (int m = 0; m < 4; m++)
#pragma unroll
            for (int n = 0; n < 4; n++) {
                int row = orow + m * 16, col = ocol + n * 16;
#pragma unroll
                for (int rr = 0; rr < 4; rr++)
                    C[(size_t)(row + rr) * N + col] = f2bf(gelu_tanh(acc[m][n][rr]));
            }
    } else {
        float* C = (float*)Cout + (size_t)e * M * N;
#pragma unroll
        for (int m = 0; m < 4; m++)
#pragma unroll
            for (int n = 0; n < 4; n++) {
                int row = orow + m * 16, col = ocol + n * 16;
#pragma unroll
                for (int rr = 0; rr < 4; rr++)
                    C[(size_t)(row + rr) * N + col] = acc[m][n][rr];
            }
    }
}

// ---------- fallback: fused fp32, zero workspace (correctness insurance) ----------

__global__ void fused_fallback(const float* __restrict__ x,
                               const float* __restrict__ w1,
                               const float* __restrict__ w2,
                               float* __restrict__ out) {
    __shared__ float xs[HID];
    __shared__ float hs[FFN];
    const int tok = blockIdx.x;
    const int e   = tok / TPE;
    const float* w1e = w1 + (size_t)e * FFN * HID;
    const float* w2e = w2 + (size_t)e * FFN * HID;
    const int t = threadIdx.x;
    for (int i = t; i < HID; i += 256) xs[i] = x[(size_t)tok * HID + i];
    __syncthreads();
    for (int f = t; f < FFN; f += 256) {
        const float* wr_ = w1e + (size_t)f * HID;
        float s = 0.f;
        for (int k = 0; k < HID; k++) s += xs[k] * wr_[k];
        hs[f] = gelu_tanh(s);
    }
    __syncthreads();
    for (int h = t; h < HID; h += 256) {
        float s = 0.f;
        for (int f = 0; f < FFN; f++) s += hs[f] * w2e[(size_t)f * HID + h];
        out[(size_t)tok * HID + h] = s;
    }
}

// ---------- launch ----------

extern "C" void kernel_launch(void* const* d_in, const int* in_sizes, int n_in,
                              void* d_out, int out_size, void* d_ws, size_t ws_size,
                              hipStream_t stream) {
    const float* x  = (const float*)d_in[0];
    const float* w1 = (const float*)d_in[1];
    const float* w2 = (const float*)d_in[2];
    float* out = (float*)d_out;

    const size_t XB  = (size_t)TOK * HID * 2;        // 16 MB  bf16 x
    const size_t W1B = (size_t)NE * FFN * HID * 2;   // 64 MB  bf16 w1
    const size_t W2B = W1B;                          // 64 MB  bf16 w2t
    const size_t HB  = (size_t)TOK * FFN * 2;        // 64 MB  bf16 h
    const size_t need = XB + W1B + W2B + HB;         // 208 MB

    if (ws_size >= need) {
        char* ws = (char*)d_ws;
        unsigned short* xb  = (unsigned short*)ws;
        unsigned short* w1b = (unsigned short*)(ws + XB);
        unsigned short* w2t = (unsigned short*)(ws + XB + W1B);
        unsigned short* hb  = (unsigned short*)(ws + XB + W1B + W2B);

        cvt_f32_bf16<<<(TOK * HID) / (256 * 8), 256, 0, stream>>>(x, xb);
        cvt_f32_bf16<<<(NE * FFN * HID) / (256 * 8), 256, 0, stream>>>(w1, w1b);
        transpose_cvt<<<dim3(FFN / 64, HID / 64, NE), 256, 0, stream>>>(w2, w2t);

        // GEMM1: h = gelu(x @ w1^T)  M=1024,N=4096,K=1024/expert -> 2048 blocks
        gemm_dw<TPE / 128, FFN / 128, true>
            <<<NE * (TPE / 128) * (FFN / 128), 256, 0, stream>>>(
                xb, w1b, hb, TPE, FFN, HID);
        // GEMM2: out = h @ w2t^T     M=1024,N=1024,K=4096/expert -> 512 blocks
        gemm_dw<TPE / 128, HID / 128, false>
            <<<NE * (TPE / 128) * (HID / 128), 256, 0, stream>>>(
                hb, w2t, out, TPE, HID, FFN);
    } else {
        fused_fallback<<<TOK, 256, 0, stream>>>(x, w1, w2, out);
    }
}

// Round 9
// 234.935 us; speedup vs baseline: 1.2086x; 1.1414x over previous
//
#include <hip/hip_runtime.h>
#include <hip/hip_bf16.h>
#include <stdint.h>

#define NE 8
#define HID 1024
#define FFN 4096
#define TOK 8192
#define TPE (TOK / NE)   // 1024 tokens per expert

typedef __attribute__((ext_vector_type(8))) short    bf16x8;
typedef __attribute__((ext_vector_type(4))) float    f32x4;
typedef __attribute__((ext_vector_type(4))) unsigned short ushort4v;
typedef __attribute__((ext_vector_type(8))) unsigned short ushort8v;

// ---------- helpers ----------

__device__ __forceinline__ unsigned short f2bf(float f) {
    union { float f; unsigned u; } c; c.f = f;
    unsigned r = c.u + 0x7fffu + ((c.u >> 16) & 1u);   // RNE, inputs finite
    return (unsigned short)(r >> 16);
}

__device__ __forceinline__ float gelu_tanh(float x) {
    const float c0 = 0.7978845608028654f;  // sqrt(2/pi)
    const float c1 = 0.044715f;
    float u = c0 * (x + c1 * x * x * x);
    float t = 1.0f - 2.0f / (1.0f + __expf(2.0f * u));
    return 0.5f * x * (1.0f + t);
}

typedef const __attribute__((address_space(1))) void gbl_void_t;
typedef __attribute__((address_space(3))) void lds_void_t;

__device__ __forceinline__ void gload_lds16(const void* g, void* l) {
    __builtin_amdgcn_global_load_lds((gbl_void_t*)g, (lds_void_t*)l, 16, 0, 0);
}

// ---------- fused conversion: x and w1, f32 -> bf16, one launch ----------

#define XBLKS ((TOK * HID) / 2048)           // 4096 blocks for x
#define W1BLKS ((NE * FFN * HID) / 2048)     // 16384 blocks for w1

__global__ void cvt_dual(const float* __restrict__ x, unsigned short* __restrict__ xb,
                         const float* __restrict__ w1, unsigned short* __restrict__ w1b) {
    const float* in;
    unsigned short* out;
    size_t i;
    if (blockIdx.x < XBLKS) {
        in = x; out = xb;
        i = ((size_t)blockIdx.x * 256 + threadIdx.x) * 8;
    } else {
        in = w1; out = w1b;
        i = ((size_t)(blockIdx.x - XBLKS) * 256 + threadIdx.x) * 8;
    }
    f32x4 a = *(const f32x4*)(in + i);
    f32x4 b = *(const f32x4*)(in + i + 4);
    ushort8v o;
#pragma unroll
    for (int j = 0; j < 4; j++) { o[j] = f2bf(a[j]); o[4 + j] = f2bf(b[j]); }
    *(ushort8v*)(out + i) = o;
}

// ---------- transpose-convert: w2 [E][F][H] f32 -> w2t [E][H][F] bf16 ----------

__global__ void transpose_cvt(const float* __restrict__ in,
                              unsigned short* __restrict__ out) {
    __shared__ unsigned short tile[64][65];
    const int e  = blockIdx.z;
    const int f0 = blockIdx.x * 64;
    const int h0 = blockIdx.y * 64;
    const float*     src = in  + (size_t)e * FFN * HID;
    unsigned short*  dst = out + (size_t)e * HID * FFN;
    const int t  = threadIdx.x;
    const int tr = t >> 4;        // 0..15
    const int tc = (t & 15) * 4;  // 0..60
#pragma unroll
    for (int i = 0; i < 4; i++) {
        int f = i * 16 + tr;
        f32x4 v = *(const f32x4*)(src + (size_t)(f0 + f) * HID + h0 + tc);
#pragma unroll
        for (int j = 0; j < 4; j++) tile[f][tc + j] = f2bf(v[j]);
    }
    __syncthreads();
#pragma unroll
    for (int i = 0; i < 4; i++) {
        int h = i * 16 + tr;
        ushort4v o;
#pragma unroll
        for (int j = 0; j < 4; j++) o[j] = tile[tc + j][h];
        *(ushort4v*)(dst + (size_t)(h0 + h) * FFN + f0 + tc) = o;
    }
}

// ---------- 8-phase GEMM-BT (R4 schedule + earlier B-staging) --------------
// C[M][N] = A[M][K] * B[N][K]^T per expert. BM=256, BK=64, 8 waves (2Mx4N),
// 512 threads, double-buffered LDS, T2 XOR swizzle (linear dest /
// pre-swizzled source / swizzled read), counted vmcnt at ph4/ph8 only,
// setprio around MFMA. Stage stream (earlier-B variant):
//   ph1:A1(T+1) ph2:A0(T+2) ph3:B0,B1(T+2) ph4:VMW
//   ph5:A1(T+2) ph6:A0(T+3) ph7:B0,B1(T+3) ph8:VMW
// FIFO at ph4 VMW(6): outstanding 6(prev)+2+2+4 = 14 -> drain 8 oldest =
// {A0,B0,B1}(T+1)+A1(T+1) -> tile T+1 fully published; 6 of T+2 in flight.

template <int BN, int GX, int GY, bool GELU>
__global__ __launch_bounds__(512, 2)
void gemm8p(const unsigned short* __restrict__ A,
            const unsigned short* __restrict__ B,
            void* __restrict__ Cout, int M, int N, int K) {
    constexpr int BM = 256, BK = 64;
    constexpr int NH = BN / 128;          // n-frags per quad (2 or 1)
    constexpr int NI = 2 * NH;            // n-frags per wave
    constexpr int LB = BN / 128;          // loads per B-unit per thread
    constexpr int S  = BN / 8;            // B-unit row-group half-stride
    constexpr int ABYTES = BM * BK * 2;   // 32768
    constexpr int BBYTES = BN * BK * 2;   // 32768 / 16384
    constexpr int BUF = ABYTES + BBYTES;
    constexpr int VMC = 2 + 2 * LB;       // 6 (BN=256) or 4 (BN=128)
    constexpr int NWG = NE * GX * GY;     // flat grid size (multiple of 8)

    __shared__ __align__(16) char lds[2 * BUF];

    // ---- XCD-aware bijective swizzle (T1) ----
    const int lin = blockIdx.x;
    const int wid = (lin & 7) * (NWG >> 3) + (lin >> 3);
    const int e   = wid / (GX * GY);
    const int rem = wid % (GX * GY);
    const int m0  = (rem % GX) * BM;
    const int n0  = (rem / GX) * BN;

    const size_t K2 = (size_t)K * 2;
    const char* Ae = (const char*)(A + (size_t)e * M * K);
    const char* Be = (const char*)(B + (size_t)e * N * K);

    const int tid  = threadIdx.x;
    const int lane = tid & 63;
    const int w    = tid >> 6;
    const int wr   = w >> 2, wc = w & 3;
    const int fr   = lane & 15, fq = lane >> 4;

    // ---- staging addressing (rule #21: linear LDS dest, pre-swizzled src) ----
    const int rA  = tid >> 3;             // 0..63
    const int kb  = (tid & 7) * 16;       // byte offset in 128B row
    const int kbs = kb ^ ((rA & 7) << 4); // swizzled source k-offset
    const char* aptr = Ae + (size_t)(m0 + rA) * K2 + kbs;
    const int   fB   = (rA / S) * 2 * S + (rA % S);
    const char* bptr = Be + (size_t)(n0 + fB) * K2 + kbs;
    char* dA0 = lds + rA * 128 + kb;      // wave-linear dest (base + lane*16)
    char* dA1 = dA0 + BUF;
    char* dB0 = lds + ABYTES + fB * 128 + kb;
    char* dB1 = dB0 + BUF;

    auto SA = [&](int au, int kt, char* d) {      // stage A-unit au of tile kt
        const char* s = aptr + (size_t)kt * 128;
#pragma unroll
        for (int i = 0; i < 2; i++)
            gload_lds16(s + (size_t)(au * 64 + i * 128) * K2,
                        d + (au * 64 + i * 128) * 128);
    };
    auto SB = [&](int bu, int kt, char* d) {      // stage B-unit bu of tile kt
        const char* s = bptr + (size_t)kt * 128;
#pragma unroll
        for (int i = 0; i < LB; i++)
            gload_lds16(s + (size_t)(bu * S + i * 128) * K2,
                        d + (bu * S + i * 128) * 128);
    };

    // ---- LDS read base pointers (swizzled reads) ----
    const int kx0 = (fq * 16) ^ ((lane & 7) << 4);
    const char* paA = lds + (wr * 128 + fr) * 128;
    const char* paB = lds + ABYTES + (wc * (BN / 4) + fr) * 128;
    const char* pa0k0 = paA + kx0;        const char* pa0k1 = paA + (kx0 ^ 64);
    const char* pa1k0 = pa0k0 + BUF;      const char* pa1k1 = pa0k1 + BUF;
    const char* pb0k0 = paB + kx0;        const char* pb0k1 = paB + (kx0 ^ 64);
    const char* pb1k0 = pb0k0 + BUF;      const char* pb1k1 = pb0k1 + BUF;

    f32x4 acc[8][NI];
#pragma unroll
    for (int i = 0; i < 8; i++)
#pragma unroll
        for (int j = 0; j < NI; j++) acc[i][j] = f32x4{0.f, 0.f, 0.f, 0.f};

    bf16x8 a[4][2], b0[NH][2], b1[NH][2];

    auto LDA = [&](const char* p0, const char* p1, int mq) {
#pragma unroll
        for (int mi = 0; mi < 4; mi++) {
            a[mi][0] = *(const bf16x8*)(p0 + mq * 8192 + mi * 2048);
            a[mi][1] = *(const bf16x8*)(p1 + mq * 8192 + mi * 2048);
        }
    };
    auto LDB = [&](const char* p0, const char* p1, int nq, bf16x8 (&bb)[NH][2]) {
#pragma unroll
        for (int ni = 0; ni < NH; ni++) {
            bb[ni][0] = *(const bf16x8*)(p0 + (nq * (BN / 8) + ni * 16) * 128);
            bb[ni][1] = *(const bf16x8*)(p1 + (nq * (BN / 8) + ni * 16) * 128);
        }
    };
    auto MMQ = [&](int mq, int nq, bf16x8 (&bb)[NH][2]) {
        __builtin_amdgcn_s_setprio(1);
#pragma unroll
        for (int mi = 0; mi < 4; mi++)
#pragma unroll
            for (int ni = 0; ni < NH; ni++) {
                f32x4& c = acc[mq * 4 + mi][nq * NH + ni];
                c = __builtin_amdgcn_mfma_f32_16x16x32_bf16(a[mi][0], bb[ni][0], c, 0, 0, 0);
                c = __builtin_amdgcn_mfma_f32_16x16x32_bf16(a[mi][1], bb[ni][1], c, 0, 0, 0);
            }
        __builtin_amdgcn_s_setprio(0);
    };

    // Minimal-pin barrier discipline:
#define MIDBAR()  __builtin_amdgcn_s_barrier();                                      \
                  asm volatile("s_waitcnt lgkmcnt(0)" ::: "memory");                 \
                  __builtin_amdgcn_sched_barrier(0)          /* rule #18 */
#define ENDBAR()  __builtin_amdgcn_s_barrier();                                      \
                  __builtin_amdgcn_sched_barrier(0)          /* no read hoist */
#define LGHINT()  asm volatile("s_waitcnt lgkmcnt(8)" ::: "memory")
#define VMW()     asm volatile("s_waitcnt vmcnt(%0)" :: "n"(VMC) : "memory")

    const int NT   = K / BK;
    const int NTm1 = NT - 1;

    // prologue: tile0 all units, tile1 {A0,B0,B1}; drain tile0, keep 6
    SA(0, 0, dA0); SB(0, 0, dB0); SB(1, 0, dB0); SA(1, 0, dA0);
    SA(0, 1, dA1); SB(0, 1, dB1); SB(1, 1, dB1);
    VMW();
    __builtin_amdgcn_s_barrier();
    __builtin_amdgcn_sched_barrier(0);

    const int NW = NT / 2;
    for (int ww = 0; ww < NW; ++ww) {
        const int T = 2 * ww;
        const int kt1 = T + 1;                          // always < NT
        const int kt2 = (T + 2 < NT) ? T + 2 : NTm1;
        const int kt3 = (T + 3 < NT) ? T + 3 : NTm1;

        // ---- buf0 half: tile T ----
        LDA(pa0k0, pa0k1, 0); LDB(pb0k0, pb0k1, 0, b0); SA(1, kt1, dA1);
        LGHINT(); MIDBAR(); MMQ(0, 0, b0); ENDBAR();             // ph1
        LDB(pb0k0, pb0k1, 1, b1); SA(0, kt2, dA0);
        MIDBAR(); MMQ(0, 1, b1); ENDBAR();                       // ph2
        LDA(pa0k0, pa0k1, 1); SB(0, kt2, dB0); SB(1, kt2, dB0);
        MIDBAR(); MMQ(1, 1, b1); ENDBAR();                       // ph3
        MIDBAR(); MMQ(1, 0, b0); VMW(); ENDBAR();                // ph4
        // ---- buf1 half: tile T+1 ----
        LDA(pa1k0, pa1k1, 0); LDB(pb1k0, pb1k1, 0, b0); SA(1, kt2, dA0);
        LGHINT(); MIDBAR(); MMQ(0, 0, b0); ENDBAR();             // ph5
        LDB(pb1k0, pb1k1, 1, b1); SA(0, kt3, dA1);
        MIDBAR(); MMQ(0, 1, b1); ENDBAR();                       // ph6
        LDA(pa1k0, pa1k1, 1); SB(0, kt3, dB1); SB(1, kt3, dB1);
        MIDBAR(); MMQ(1, 1, b1); ENDBAR();                       // ph7
        MIDBAR(); MMQ(1, 0, b0); VMW(); ENDBAR();                // ph8
    }
    asm volatile("s_waitcnt vmcnt(0)" ::: "memory");   // drain tail junk stages

    // epilogue: C/D layout col = lane&15, row = (lane>>4)*4 + r
    const int r0 = m0 + wr * 128 + fq * 4;
    const int c0 = n0 + wc * (BN / 4) + fr;
    if constexpr (GELU) {
        unsigned short* C = (unsigned short*)Cout + (size_t)e * M * N;
#pragma unroll
        for (int mi = 0; mi < 8; mi++)
#pragma unroll
            for (int ni = 0; ni < NI; ni++) {
                int row = r0 + mi * 16, col = c0 + ni * 16;
#pragma unroll
                for (int r = 0; r < 4; r++)
                    C[(size_t)(row + r) * N + col] = f2bf(gelu_tanh(acc[mi][ni][r]));
            }
    } else {
        float* C = (float*)Cout + (size_t)e * M * N;
#pragma unroll
        for (int mi = 0; mi < 8; mi++)
#pragma unroll
            for (int ni = 0; ni < NI; ni++) {
                int row = r0 + mi * 16, col = c0 + ni * 16;
#pragma unroll
                for (int r = 0; r < 4; r++)
                    C[(size_t)(row + r) * N + col] = acc[mi][ni][r];
            }
    }
#undef MIDBAR
#undef ENDBAR
#undef LGHINT
#undef VMW
}

// ---------- fallback: fused fp32, zero workspace (correctness insurance) ----------

__global__ void fused_fallback(const float* __restrict__ x,
                               const float* __restrict__ w1,
                               const float* __restrict__ w2,
                               float* __restrict__ out) {
    __shared__ float xs[HID];
    __shared__ float hs[FFN];
    const int tok = blockIdx.x;
    const int e   = tok / TPE;
    const float* w1e = w1 + (size_t)e * FFN * HID;
    const float* w2e = w2 + (size_t)e * FFN * HID;
    const int t = threadIdx.x;
    for (int i = t; i < HID; i += 256) xs[i] = x[(size_t)tok * HID + i];
    __syncthreads();
    for (int f = t; f < FFN; f += 256) {
        const float* wr_ = w1e + (size_t)f * HID;
        float s = 0.f;
        for (int k = 0; k < HID; k++) s += xs[k] * wr_[k];
        hs[f] = gelu_tanh(s);
    }
    __syncthreads();
    for (int h = t; h < HID; h += 256) {
        float s = 0.f;
        for (int f = 0; f < FFN; f++) s += hs[f] * w2e[(size_t)f * HID + h];
        out[(size_t)tok * HID + h] = s;
    }
}

// ---------- launch ----------

extern "C" void kernel_launch(void* const* d_in, const int* in_sizes, int n_in,
                              void* d_out, int out_size, void* d_ws, size_t ws_size,
                              hipStream_t stream) {
    const float* x  = (const float*)d_in[0];
    const float* w1 = (const float*)d_in[1];
    const float* w2 = (const float*)d_in[2];
    float* out = (float*)d_out;

    const size_t XB  = (size_t)TOK * HID * 2;        // 16 MB  bf16 x
    const size_t W1B = (size_t)NE * FFN * HID * 2;   // 64 MB  bf16 w1
    const size_t W2B = W1B;                          // 64 MB  bf16 w2t
    const size_t HB  = (size_t)TOK * FFN * 2;        // 64 MB  bf16 h
    const size_t need = XB + W1B + W2B + HB;         // 208 MB

    if (ws_size >= need) {
        char* ws = (char*)d_ws;
        unsigned short* xb  = (unsigned short*)ws;
        unsigned short* w1b = (unsigned short*)(ws + XB);
        unsigned short* w2t = (unsigned short*)(ws + XB + W1B);
        unsigned short* hb  = (unsigned short*)(ws + XB + W1B + W2B);

        cvt_dual<<<XBLKS + W1BLKS, 256, 0, stream>>>(x, xb, w1, w1b);
        transpose_cvt<<<dim3(FFN / 64, HID / 64, NE), 256, 0, stream>>>(w2, w2t);

        // GEMM1: h = gelu(x @ w1^T)  M=1024,N=4096,K=1024/expert -> 512 blocks flat
        gemm8p<256, TPE / 256, FFN / 256, true><<<NE * (TPE / 256) * (FFN / 256), 512, 0, stream>>>(
            xb, w1b, hb, TPE, FFN, HID);
        // GEMM2: out = h @ w2t^T     M=1024,N=1024,K=4096/expert -> 256 blocks flat
        gemm8p<128, TPE / 256, HID / 128, false><<<NE * (TPE / 256) * (HID / 128), 512, 0, stream>>>(
            hb, w2t, out, TPE, HID, FFN);
    } else {
        fused_fallback<<<TOK, 256, 0, stream>>>(x, w1, w2, out);
    }
}

// Round 10
// 232.360 us; speedup vs baseline: 1.2220x; 1.0111x over previous
//
#include <hip/hip_runtime.h>
#include <hip/hip_bf16.h>
#include <stdint.h>

#define NE 8
#define HID 1024
#define FFN 4096
#define TOK 8192
#define TPE (TOK / NE)   // 1024 tokens per expert

typedef __attribute__((ext_vector_type(8))) short    bf16x8;
typedef __attribute__((ext_vector_type(4))) float    f32x4;
typedef __attribute__((ext_vector_type(4))) unsigned short ushort4v;
typedef __attribute__((ext_vector_type(8))) unsigned short ushort8v;

// ---------- helpers ----------

__device__ __forceinline__ unsigned short f2bf(float f) {
    union { float f; unsigned u; } c; c.f = f;
    unsigned r = c.u + 0x7fffu + ((c.u >> 16) & 1u);   // RNE, inputs finite
    return (unsigned short)(r >> 16);
}

__device__ __forceinline__ float gelu_tanh(float x) {
    const float c0 = 0.7978845608028654f;  // sqrt(2/pi)
    const float c1 = 0.044715f;
    float u = c0 * (x + c1 * x * x * x);
    float t = 1.0f - 2.0f / (1.0f + __expf(2.0f * u));
    return 0.5f * x * (1.0f + t);
}

typedef const __attribute__((address_space(1))) void gbl_void_t;
typedef __attribute__((address_space(3))) void lds_void_t;

__device__ __forceinline__ void gload_lds16(const void* g, void* l) {
    __builtin_amdgcn_global_load_lds((gbl_void_t*)g, (lds_void_t*)l, 16, 0, 0);
}

// ---------- merged prep: cvt x, cvt w1, transpose-cvt w2 (one launch) ------

#define XBLKS  ((TOK * HID) / 2048)              // 4096
#define W1BLKS ((NE * FFN * HID) / 2048)         // 16384
#define TBLKS  (NE * (FFN / 64) * (HID / 64))    // 8192

__global__ void prep_all(const float* __restrict__ x,  unsigned short* __restrict__ xb,
                         const float* __restrict__ w1, unsigned short* __restrict__ w1b,
                         const float* __restrict__ w2, unsigned short* __restrict__ w2t) {
    __shared__ unsigned short tile[64][65];
    int bid = blockIdx.x;
    if (bid < XBLKS + W1BLKS) {
        const float* in; unsigned short* out; size_t i;
        if (bid < XBLKS) { in = x;  out = xb;  i = ((size_t)bid * 256 + threadIdx.x) * 8; }
        else             { in = w1; out = w1b; i = ((size_t)(bid - XBLKS) * 256 + threadIdx.x) * 8; }
        f32x4 a = *(const f32x4*)(in + i);
        f32x4 b = *(const f32x4*)(in + i + 4);
        ushort8v o;
#pragma unroll
        for (int j = 0; j < 4; j++) { o[j] = f2bf(a[j]); o[4 + j] = f2bf(b[j]); }
        *(ushort8v*)(out + i) = o;
        return;
    }
    bid -= XBLKS + W1BLKS;
    const int e  = bid / ((FFN / 64) * (HID / 64));
    const int r_ = bid % ((FFN / 64) * (HID / 64));
    const int f0 = (r_ / (HID / 64)) * 64;
    const int h0 = (r_ % (HID / 64)) * 64;
    const float*     src = w2  + (size_t)e * FFN * HID;
    unsigned short*  dst = w2t + (size_t)e * HID * FFN;
    const int t  = threadIdx.x;
    const int tr = t >> 4;        // 0..15
    const int tc = (t & 15) * 4;  // 0..60
#pragma unroll
    for (int i = 0; i < 4; i++) {
        int f = i * 16 + tr;
        f32x4 v = *(const f32x4*)(src + (size_t)(f0 + f) * HID + h0 + tc);
#pragma unroll
        for (int j = 0; j < 4; j++) tile[f][tc + j] = f2bf(v[j]);
    }
    __syncthreads();
#pragma unroll
    for (int i = 0; i < 4; i++) {
        int h = i * 16 + tr;
        ushort4v o;
#pragma unroll
        for (int j = 0; j < 4; j++) o[j] = tile[tc + j][h];
        *(ushort4v*)(dst + (size_t)(h0 + h) * FFN + f0 + tc) = o;
    }
}

// ---------- 8-phase GEMM-BT (R9 schedule + deferred-drain register reads) --
// C[M][N] = A[M][K] * B[N][K]^T per expert. BM=256, BK=64, 8 waves (2Mx4N),
// 512 threads, double-buffered LDS, T2 XOR swizzle (linear dest /
// pre-swizzled source / swizzled read), counted vmcnt at ph4/ph8 only,
// setprio around MFMA, T1 bijective XCD swizzle.
//
// KEY CHANGE vs R9: each phase's ds_reads are issued in the PREVIOUS phase
// after its MFMA cluster, so they retire during [MFMA issue + ENDBAR wait +
// next barrier] instead of being drained cold by their own phase's
// lgkmcnt(0). Hazards: b1(T) post-ph1 reads complete at ph2 MIDBAR, 2
// barriers before ph3's B1(T+2) stage; a1(T) post-ph2 reads complete 2
// barriers before ph5's A1(T+2) stage. ph5's a0/b0 reads stay at phase
// start (publish boundary = ph4 VMW+ENDBAR). ENDBAR pins retained: they
// stop STAGE hoisting above the region-free barrier (the actual race).

template <int BN, int GX, int GY, bool GELU>
__global__ __launch_bounds__(512, 2)
void gemm8p(const unsigned short* __restrict__ A,
            const unsigned short* __restrict__ B,
            void* __restrict__ Cout, int M, int N, int K) {
    constexpr int BM = 256, BK = 64;
    constexpr int NH = BN / 128;          // n-frags per quad (2 or 1)
    constexpr int NI = 2 * NH;            // n-frags per wave
    constexpr int LB = BN / 128;          // loads per B-unit per thread
    constexpr int S  = BN / 8;            // B-unit row-group half-stride
    constexpr int ABYTES = BM * BK * 2;   // 32768
    constexpr int BBYTES = BN * BK * 2;   // 32768 / 16384
    constexpr int BUF = ABYTES + BBYTES;
    constexpr int VMC = 2 + 2 * LB;       // 6 (BN=256) or 4 (BN=128)
    constexpr int NWG = NE * GX * GY;     // flat grid size (multiple of 8)

    __shared__ __align__(16) char lds[2 * BUF];

    // ---- XCD-aware bijective swizzle (T1) ----
    const int lin = blockIdx.x;
    const int wid = (lin & 7) * (NWG >> 3) + (lin >> 3);
    const int e   = wid / (GX * GY);
    const int rem = wid % (GX * GY);
    const int m0  = (rem % GX) * BM;
    const int n0  = (rem / GX) * BN;

    const size_t K2 = (size_t)K * 2;
    const char* Ae = (const char*)(A + (size_t)e * M * K);
    const char* Be = (const char*)(B + (size_t)e * N * K);

    const int tid  = threadIdx.x;
    const int lane = tid & 63;
    const int w    = tid >> 6;
    const int wr   = w >> 2, wc = w & 3;
    const int fr   = lane & 15, fq = lane >> 4;

    // ---- staging addressing (rule #21: linear LDS dest, pre-swizzled src) ----
    const int rA  = tid >> 3;             // 0..63
    const int kb  = (tid & 7) * 16;       // byte offset in 128B row
    const int kbs = kb ^ ((rA & 7) << 4); // swizzled source k-offset
    const char* aptr = Ae + (size_t)(m0 + rA) * K2 + kbs;
    const int   fB   = (rA / S) * 2 * S + (rA % S);
    const char* bptr = Be + (size_t)(n0 + fB) * K2 + kbs;
    char* dA0 = lds + rA * 128 + kb;      // wave-linear dest (base + lane*16)
    char* dA1 = dA0 + BUF;
    char* dB0 = lds + ABYTES + fB * 128 + kb;
    char* dB1 = dB0 + BUF;

    auto SA = [&](int au, int kt, char* d) {      // stage A-unit au of tile kt
        const char* s = aptr + (size_t)kt * 128;
#pragma unroll
        for (int i = 0; i < 2; i++)
            gload_lds16(s + (size_t)(au * 64 + i * 128) * K2,
                        d + (au * 64 + i * 128) * 128);
    };
    auto SB = [&](int bu, int kt, char* d) {      // stage B-unit bu of tile kt
        const char* s = bptr + (size_t)kt * 128;
#pragma unroll
        for (int i = 0; i < LB; i++)
            gload_lds16(s + (size_t)(bu * S + i * 128) * K2,
                        d + (bu * S + i * 128) * 128);
    };

    // ---- LDS read base pointers (swizzled reads) ----
    const int kx0 = (fq * 16) ^ ((lane & 7) << 4);
    const char* paA = lds + (wr * 128 + fr) * 128;
    const char* paB = lds + ABYTES + (wc * (BN / 4) + fr) * 128;
    const char* pa0k0 = paA + kx0;        const char* pa0k1 = paA + (kx0 ^ 64);
    const char* pa1k0 = pa0k0 + BUF;      const char* pa1k1 = pa0k1 + BUF;
    const char* pb0k0 = paB + kx0;        const char* pb0k1 = paB + (kx0 ^ 64);
    const char* pb1k0 = pb0k0 + BUF;      const char* pb1k1 = pb0k1 + BUF;

    f32x4 acc[8][NI];
#pragma unroll
    for (int i = 0; i < 8; i++)
#pragma unroll
        for (int j = 0; j < NI; j++) acc[i][j] = f32x4{0.f, 0.f, 0.f, 0.f};

    bf16x8 a[4][2], b0[NH][2], b1[NH][2];

    auto LDA = [&](const char* p0, const char* p1, int mq) {
#pragma unroll
        for (int mi = 0; mi < 4; mi++) {
            a[mi][0] = *(const bf16x8*)(p0 + mq * 8192 + mi * 2048);
            a[mi][1] = *(const bf16x8*)(p1 + mq * 8192 + mi * 2048);
        }
    };
    auto LDB = [&](const char* p0, const char* p1, int nq, bf16x8 (&bb)[NH][2]) {
#pragma unroll
        for (int ni = 0; ni < NH; ni++) {
            bb[ni][0] = *(const bf16x8*)(p0 + (nq * (BN / 8) + ni * 16) * 128);
            bb[ni][1] = *(const bf16x8*)(p1 + (nq * (BN / 8) + ni * 16) * 128);
        }
    };
    auto MMQ = [&](int mq, int nq, bf16x8 (&bb)[NH][2]) {
        __builtin_amdgcn_s_setprio(1);
#pragma unroll
        for (int mi = 0; mi < 4; mi++)
#pragma unroll
            for (int ni = 0; ni < NH; ni++) {
                f32x4& c = acc[mq * 4 + mi][nq * NH + ni];
                c = __builtin_amdgcn_mfma_f32_16x16x32_bf16(a[mi][0], bb[ni][0], c, 0, 0, 0);
                c = __builtin_amdgcn_mfma_f32_16x16x32_bf16(a[mi][1], bb[ni][1], c, 0, 0, 0);
            }
        __builtin_amdgcn_s_setprio(0);
    };

#define MIDBAR()  __builtin_amdgcn_s_barrier();                                      \
                  asm volatile("s_waitcnt lgkmcnt(0)" ::: "memory");                 \
                  __builtin_amdgcn_sched_barrier(0)          /* rule #18 */
#define ENDBAR()  __builtin_amdgcn_s_barrier();                                      \
                  __builtin_amdgcn_sched_barrier(0)          /* no stage/read hoist */
#define LGHINT()  asm volatile("s_waitcnt lgkmcnt(8)" ::: "memory")
#define VMW()     asm volatile("s_waitcnt vmcnt(%0)" :: "n"(VMC) : "memory")

    const int NT   = K / BK;
    const int NTm1 = NT - 1;

    // prologue: tile0 all units, tile1 {A0,B0,B1}; drain tile0, keep 6
    SA(0, 0, dA0); SB(0, 0, dB0); SB(1, 0, dB0); SA(1, 0, dA0);
    SA(0, 1, dA1); SB(0, 1, dB1); SB(1, 1, dB1);
    VMW();
    __builtin_amdgcn_s_barrier();
    __builtin_amdgcn_sched_barrier(0);

    const int NW = NT / 2;
    for (int ww = 0; ww < NW; ++ww) {
        const int T = 2 * ww;
        const int kt1 = T + 1;                          // always < NT
        const int kt2 = (T + 2 < NT) ? T + 2 : NTm1;
        const int kt3 = (T + 3 < NT) ? T + 3 : NTm1;

        // ---- buf0 half: tile T ----
        LDA(pa0k0, pa0k1, 0); LDB(pb0k0, pb0k1, 0, b0); SA(1, kt1, dA1);
        LGHINT(); MIDBAR(); MMQ(0, 0, b0);
        LDB(pb0k0, pb0k1, 1, b1); ENDBAR();                      // ph1 (+b1 reads hidden)
        SA(0, kt2, dA0);
        MIDBAR(); MMQ(0, 1, b1);
        LDA(pa0k0, pa0k1, 1); ENDBAR();                          // ph2 (+a1 reads hidden)
        SB(0, kt2, dB0); SB(1, kt2, dB0);
        MIDBAR(); MMQ(1, 1, b1); ENDBAR();                       // ph3
        MIDBAR(); MMQ(1, 0, b0); VMW(); ENDBAR();                // ph4
        // ---- buf1 half: tile T+1 ----
        LDA(pa1k0, pa1k1, 0); LDB(pb1k0, pb1k1, 0, b0); SA(1, kt2, dA0);
        LGHINT(); MIDBAR(); MMQ(0, 0, b0);
        LDB(pb1k0, pb1k1, 1, b1); ENDBAR();                      // ph5
        SA(0, kt3, dA1);
        MIDBAR(); MMQ(0, 1, b1);
        LDA(pa1k0, pa1k1, 1); ENDBAR();                          // ph6
        SB(0, kt3, dB1); SB(1, kt3, dB1);
        MIDBAR(); MMQ(1, 1, b1); ENDBAR();                       // ph7
        MIDBAR(); MMQ(1, 0, b0); VMW(); ENDBAR();                // ph8
    }
    asm volatile("s_waitcnt vmcnt(0)" ::: "memory");   // drain tail junk stages

    // epilogue: C/D layout col = lane&15, row = (lane>>4)*4 + r
    const int r0 = m0 + wr * 128 + fq * 4;
    const int c0 = n0 + wc * (BN / 4) + fr;
    if constexpr (GELU) {
        unsigned short* C = (unsigned short*)Cout + (size_t)e * M * N;
#pragma unroll
        for (int mi = 0; mi < 8; mi++)
#pragma unroll
            for (int ni = 0; ni < NI; ni++) {
                int row = r0 + mi * 16, col = c0 + ni * 16;
#pragma unroll
                for (int r = 0; r < 4; r++)
                    C[(size_t)(row + r) * N + col] = f2bf(gelu_tanh(acc[mi][ni][r]));
            }
    } else {
        float* C = (float*)Cout + (size_t)e * M * N;
#pragma unroll
        for (int mi = 0; mi < 8; mi++)
#pragma unroll
            for (int ni = 0; ni < NI; ni++) {
                int row = r0 + mi * 16, col = c0 + ni * 16;
#pragma unroll
                for (int r = 0; r < 4; r++)
                    C[(size_t)(row + r) * N + col] = acc[mi][ni][r];
            }
    }
#undef MIDBAR
#undef ENDBAR
#undef LGHINT
#undef VMW
}

// ---------- fallback: fused fp32, zero workspace (correctness insurance) ----------

__global__ void fused_fallback(const float* __restrict__ x,
                               const float* __restrict__ w1,
                               const float* __restrict__ w2,
                               float* __restrict__ out) {
    __shared__ float xs[HID];
    __shared__ float hs[FFN];
    const int tok = blockIdx.x;
    const int e   = tok / TPE;
    const float* w1e = w1 + (size_t)e * FFN * HID;
    const float* w2e = w2 + (size_t)e * FFN * HID;
    const int t = threadIdx.x;
    for (int i = t; i < HID; i += 256) xs[i] = x[(size_t)tok * HID + i];
    __syncthreads();
    for (int f = t; f < FFN; f += 256) {
        const float* wr_ = w1e + (size_t)f * HID;
        float s = 0.f;
        for (int k = 0; k < HID; k++) s += xs[k] * wr_[k];
        hs[f] = gelu_tanh(s);
    }
    __syncthreads();
    for (int h = t; h < HID; h += 256) {
        float s = 0.f;
        for (int f = 0; f < FFN; f++) s += hs[f] * w2e[(size_t)f * HID + h];
        out[(size_t)tok * HID + h] = s;
    }
}

// ---------- launch ----------

extern "C" void kernel_launch(void* const* d_in, const int* in_sizes, int n_in,
                              void* d_out, int out_size, void* d_ws, size_t ws_size,
                              hipStream_t stream) {
    const float* x  = (const float*)d_in[0];
    const float* w1 = (const float*)d_in[1];
    const float* w2 = (const float*)d_in[2];
    float* out = (float*)d_out;

    const size_t XB  = (size_t)TOK * HID * 2;        // 16 MB  bf16 x
    const size_t W1B = (size_t)NE * FFN * HID * 2;   // 64 MB  bf16 w1
    const size_t W2B = W1B;                          // 64 MB  bf16 w2t
    const size_t HB  = (size_t)TOK * FFN * 2;        // 64 MB  bf16 h
    const size_t need = XB + W1B + W2B + HB;         // 208 MB

    if (ws_size >= need) {
        char* ws = (char*)d_ws;
        unsigned short* xb  = (unsigned short*)ws;
        unsigned short* w1b = (unsigned short*)(ws + XB);
        unsigned short* w2t = (unsigned short*)(ws + XB + W1B);
        unsigned short* hb  = (unsigned short*)(ws + XB + W1B + W2B);

        prep_all<<<XBLKS + W1BLKS + TBLKS, 256, 0, stream>>>(x, xb, w1, w1b, w2, w2t);

        // GEMM1: h = gelu(x @ w1^T)  M=1024,N=4096,K=1024/expert -> 512 blocks flat
        gemm8p<256, TPE / 256, FFN / 256, true><<<NE * (TPE / 256) * (FFN / 256), 512, 0, stream>>>(
            xb, w1b, hb, TPE, FFN, HID);
        // GEMM2: out = h @ w2t^T     M=1024,N=1024,K=4096/expert -> 256 blocks flat
        gemm8p<128, TPE / 256, HID / 128, false><<<NE * (TPE / 256) * (HID / 128), 512, 0, stream>>>(
            hb, w2t, out, TPE, HID, FFN);
    } else {
        fused_fallback<<<TOK, 256, 0, stream>>>(x, w1, w2, out);
    }
}